// Round 8
// baseline (170.678 us; speedup 1.0000x reference)
//
#include <hip/hip_runtime.h>
#include <cstdint>
#include <cstddef>

// Problem constants (from reference setup_inputs)
#define BB   8
#define NN   2048
#define DD   16
#define HHH  64
#define KK   32
#define CAP  96          // max within-R hits kept incl self (mean ~37, Poisson tail safe)
#define FCAP 48          // max fwd neighbors kept (<=32 barring exact d2 ties)
#define DT_C 0.01f
#define R2_C (0.08f * 0.08f)
#define CEXP (-2.885390081777927f)   // -2*log2(e):  exp(-2|z|) = exp2(CEXP*|z|)

#define BANDS    18
#define BAND_OFF 0.72f
#define BAND_INV 12.5f   // 1/0.08; bands cover y in [-0.72,0.72], clamped at edges

#define WPB   8                 // waves per block (1 particle per wave)
#define BLOCK (WPB * 64)

// Same rounding as the reference's sum-of-squares (sub,sub,mul,mul,add; no fma).
__device__ __forceinline__ float dist2(float px, float py, float qx, float qy) {
    float dx = __fsub_rn(px, qx);
    float dy = __fsub_rn(py, qy);
    return __fadd_rn(__fmul_rn(dx, dx), __fmul_rn(dy, dy));
}

// v_mbcnt_lo/hi natively count set bits among lanes BELOW the caller: prefix count.
__device__ __forceinline__ int prefix_cnt(unsigned long long m) {
    return (int)__builtin_amdgcn_mbcnt_hi(
        (unsigned)(m >> 32), __builtin_amdgcn_mbcnt_lo((unsigned)m, 0u));
}

// XCD-aware swizzle: batch = blockIdx & 7 so each XCD's L2 caches one batch's
// sortedPos/cut/AD/cand slices. Heuristic only — correctness-free.
__device__ __forceinline__ int swizzled_particle(int blk, int w, int& bbase) {
    int vb = blk & 7, vi = blk >> 3;
    bbase = vb << 11;
    return bbase + vi * WPB + w;
}

// Per step, one block per batch: counting-sort particles into 18 y-bands of
// width R. sortedPos entries are verbatim copies -> d2 bits unchanged.
// Block 0 additionally computes v = W2 @ Wout once for the whole step.
template <bool FIRST>
__global__ __launch_bounds__(1024) void k_bin(
    const float* __restrict__ x, const float* __restrict__ pos,
    const float* __restrict__ W2, const float* __restrict__ Wout,
    float2* __restrict__ sortedPos, unsigned short* __restrict__ sortedIdx,
    int* __restrict__ bandStart, float* __restrict__ vOut) {
    __shared__ int hist[BANDS], base[BANDS + 1], cursor[BANDS];
    int bat = blockIdx.x;
    int bbase = bat << 11;
    int tid = threadIdx.x;
    if (tid < BANDS) hist[tid] = 0;
    if (blockIdx.x == 0 && tid >= 64 && tid < 64 + HHH) {   // v = W2 @ Wout
        int hh = tid - 64;
        float acc = 0.f;
        for (int c = 0; c < 32; c++) acc = fmaf(W2[hh * 32 + c], Wout[c], acc);
        vOut[hh] = acc;
    }
    __syncthreads();
    float2 q[2]; int bd[2];
#pragma unroll
    for (int u = 0; u < 2; ++u) {
        int i = tid + (u << 10);
        float2 qq;
        if (FIRST) qq = *(const float2*)(x + (size_t)(bbase + i) * DD);
        else       qq = *(const float2*)(pos + (size_t)(bbase + i) * 2);
        q[u] = qq;
        int band = (int)((qq.y + BAND_OFF) * BAND_INV);
        band = band < 0 ? 0 : (band > BANDS - 1 ? BANDS - 1 : band);
        bd[u] = band;
        atomicAdd(&hist[band], 1);
    }
    __syncthreads();
    if (tid == 0) {
        int acc = 0;
        for (int k = 0; k < BANDS; ++k) { base[k] = acc; cursor[k] = acc; acc += hist[k]; }
        base[BANDS] = acc;
    }
    __syncthreads();
    if (tid <= BANDS) bandStart[bat * 32 + tid] = base[tid];
#pragma unroll
    for (int u = 0; u < 2; ++u) {
        int i = tid + (u << 10);
        int dst = atomicAdd(&cursor[bd[u]], 1);
        sortedPos[bbase + dst] = q[u];
        sortedIdx[bbase + dst] = (unsigned short)i;   // batch-local index
    }
}

// Kernel 1 per step, one wave per particle p — fully barrier-free:
//  - A_p[h] = x_p @ W1[:16], D_p[h] = x_p @ W1[16:]  (W1 read direct from L1/L2)
//  - scan only y-bands b(p)-1..b(p)+1 of the sorted array (~410 candidates);
//    self included (d2=0 exactly) -> cutoff rank KK (0-based) instead of KK-1
//  - emit candList {d2, orig j} + pre-compacted fwd u16 list (self dropped)
__global__ __launch_bounds__(BLOCK) void k_neighbors(
    const float* __restrict__ x,
    const float2* __restrict__ sortedPos, const unsigned short* __restrict__ sortedIdx,
    const int* __restrict__ bandStart, const float* __restrict__ W1,
    float2* __restrict__ candList, unsigned short* __restrict__ fwdList,
    int* __restrict__ cntArr, float* __restrict__ cutArr,
    float* __restrict__ Aplane, float* __restrict__ Dplane) {
    __shared__ float2 sDJ[WPB][CAP];        // 6 KB packed {d2, sorted-j bits}; wave-private

    int tid = threadIdx.x;
    int w = tid >> 6, lane = tid & 63;
    int bbase;
    int p = swizzled_particle(blockIdx.x, w, bbase);
    int pl = p & (NN - 1);
    int bat = bbase >> 11;

    // ---- A/D precompute (lane = h); W1 direct from global (8 KB, cache-hot) ----
    float xv = (lane < DD) ? x[(size_t)p * DD + lane] : 0.f;
    float px = __shfl(xv, 0), py = __shfl(xv, 1);
    float A = 0.f, Dv = 0.f;
#pragma unroll
    for (int f = 0; f < DD; f++) {
        float xf = __shfl(xv, f);
        A  = fmaf(xf, W1[f * HHH + lane], A);
        Dv = fmaf(xf, W1[(DD + f) * HHH + lane], Dv);
    }
    Aplane[((size_t)p << 6) + lane] = A;
    Dplane[((size_t)p << 6) + lane] = Dv;

    // ---- banded candidate scan (self included: d2=0 < R^2 always hits) ----
    int bb = (int)((py + BAND_OFF) * BAND_INV);
    bb = bb < 0 ? 0 : (bb > BANDS - 1 ? BANDS - 1 : bb);
    int lo = bandStart[bat * 32 + (bb > 0 ? bb - 1 : 0)];
    int hi = bandStart[bat * 32 + (bb < BANDS - 1 ? bb + 2 : BANDS)];

    int cnt = 0;
    for (int c0 = lo; c0 < hi; c0 += 64) {
        int j = c0 + lane;
        float2 q = (j < hi) ? sortedPos[bbase + j] : make_float2(1e30f, 1e30f);
        float d2 = dist2(px, py, q.x, q.y);
        bool hit = (j < hi) && (d2 < R2_C);
        unsigned long long m = __ballot(hit);
        int idx = cnt + prefix_cnt(m);
        if (hit && idx < CAP)
            sDJ[w][idx] = make_float2(d2, __uint_as_float((unsigned)j));
        cnt += (int)__popcll(m);
    }
    if (cnt > CAP) cnt = CAP;
    __threadfence_block();   // wave-local LDS RAW drain

    // ---- cutoff = (KK)th value 0-based incl self == KK-th smallest among others ----
    float cutoff = R2_C;
    if (cnt > KK + 1) {
        const float INF = 1e30f;
        if (cnt <= 64) {
            float v = (lane < cnt) ? sDJ[w][lane].x : INF;
#pragma unroll
            for (int k = 2; k <= 64; k <<= 1) {
#pragma unroll
                for (int j = k >> 1; j > 0; j >>= 1) {
                    float pv = __shfl_xor(v, j);
                    bool up = ((lane & k) == 0);
                    bool takeMin = (((lane & j) == 0) == up);
                    v = takeMin ? fminf(v, pv) : fmaxf(v, pv);
                }
            }
            cutoff = __shfl(v, KK);       // ascending; rank shifted by self
        } else {                          // cnt in (64,96]: ~never, kept for correctness
            float e0 = (lane < cnt) ? sDJ[w][lane].x : INF;
            float e1 = (lane + 64 < cnt) ? sDJ[w][lane + 64].x : INF;
            int r0 = 0, q0 = 0, r1 = 0, q1 = 0;
            for (int k = 0; k < cnt; k++) {
                float val = sDJ[w][k].x;
                r0 += (val < e0); q0 += (val == e0);
                r1 += (val < e1); q1 += (val == e1);
            }
            bool c0 = (r0 <= KK) && (r0 + q0 > KK);
            bool c1 = (r1 <= KK) && (r1 + q1 > KK);
            float cand = c0 ? e0 : (c1 ? e1 : INF);
#pragma unroll
            for (int off = 32; off; off >>= 1) cand = fminf(cand, __shfl_xor(cand, off));
            cutoff = cand;
        }
    }

    // ---- emission: map sorted->orig, drop self, compact cand + fwd lists ----
    int me = 0, mf = 0;
    for (int c0 = 0; c0 < cnt; c0 += 64) {
        int c = c0 + lane;
        bool act = c < cnt;
        float2 e = sDJ[w][act ? c : 0];
        unsigned js = __float_as_uint(e.y);
        int jo = act ? (int)sortedIdx[bbase + js] : pl;
        bool keep = act && (jo != pl);
        unsigned long long mK = __ballot(keep);
        int ie = me + prefix_cnt(mK);
        if (keep)
            candList[(size_t)p * CAP + ie] = make_float2(e.x, __uint_as_float((unsigned)jo));
        me += (int)__popcll(mK);
        bool fw = keep && (e.x <= cutoff);
        unsigned long long mF = __ballot(fw);
        int iF = mf + prefix_cnt(mF);
        if (fw && iF < FCAP) fwdList[(size_t)p * FCAP + iF] = (unsigned short)jo;
        mf += (int)__popcll(mF);
    }
    if (mf > FCAP) mf = FCAP;
    if (lane == 0) { cutArr[p] = cutoff; cntArr[p] = me | (mf << 16); }
}

// Kernel 2 per step, one wave per particle p (lane = h).
__global__ __launch_bounds__(BLOCK) void k_grad(
    const float* __restrict__ x,
    const float* __restrict__ cutArr, const int* __restrict__ cntArr,
    const float2* __restrict__ candList, const unsigned short* __restrict__ fwdList,
    const float* __restrict__ Aplane, const float* __restrict__ Dplane,
    const float* __restrict__ W1, const float* __restrict__ b1,
    const float* __restrict__ vArr,
    float* __restrict__ xOut, float* __restrict__ posOut) {
    __shared__ float sW1t[HHH * 33];                       // 8.25 KB
    __shared__ alignas(16) unsigned short sFwd[WPB][FCAP]; // 768 B
    __shared__ alignas(16) unsigned short sRev[WPB][CAP];  // 1.5 KB
    __shared__ float sS[WPB][128];                         // 4 KB (~14.5 KB total)

    int tid = threadIdx.x;
    int w = tid >> 6, h = tid & 63;
    int bbase;
    int p = swizzled_particle(blockIdx.x, w, bbase);

    for (int t = tid; t < 2 * DD * HHH; t += BLOCK) {
        int f = t >> 6, hh = t & 63;
        sW1t[hh * 33 + f] = W1[t];            // pad 33: conflict-free write & read
    }
    __syncthreads();                          // the only block barrier

    float b1h = b1[h];
    float Apb = Aplane[((size_t)p << 6) + h] + b1h;
    float Dpb = Dplane[((size_t)p << 6) + h] + b1h;
    float vh4 = 4.f * vArr[h];                // precomputed in k_bin (L2-hot)
    int packed = cntArr[p];
    int cnt = packed & 0xffff;
    int mf = packed >> 16;

    // stage fwd list: one guarded coalesced copy (k1 already compacted it)
    if (h < mf) sFwd[w][h] = fwdList[(size_t)p * FCAP + h];

    // ---- rev prepass: stored d2 vs cut[j] gather, ballot-compact ----
    int mr = 0;
    for (int c0 = 0; c0 < cnt; c0 += 64) {
        int c = c0 + h;
        bool act = c < cnt;
        float2 e = candList[(size_t)p * CAP + (act ? c : 0)];
        unsigned jl = __float_as_uint(e.y) & (NN - 1);
        bool rev = act && (e.x <= cutArr[bbase + jl]);
        unsigned long long mR = __ballot(rev);
        int iR = mr + prefix_cnt(mR);
        if (rev) sRev[w][iR] = (unsigned short)jl;
        mr += (int)__popcll(mR);
    }
    __threadfence_block();

    // ---- main loops: branch-free, 16-deep gather batching, scalar-decoded ----
    const float* baseD = Dplane + ((size_t)bbase << 6);
    const float* baseA = Aplane + ((size_t)bbase << 6);
    float T1 = 0.f, T2 = 0.f;

    auto s2core = [&](float z) {
        float a = __builtin_amdgcn_exp2f(CEXP * fabsf(z));
        float bb = 1.f + a;
        return a * __builtin_amdgcn_rcpf(bb * bb);
    };

#define UNPACK8(Q0, Q1, U)                                            \
    unsigned U[8];                                                    \
    U[0] = (unsigned)__builtin_amdgcn_readfirstlane(Q0.x);            \
    U[1] = (unsigned)__builtin_amdgcn_readfirstlane(Q0.y);            \
    U[2] = (unsigned)__builtin_amdgcn_readfirstlane(Q0.z);            \
    U[3] = (unsigned)__builtin_amdgcn_readfirstlane(Q0.w);            \
    U[4] = (unsigned)__builtin_amdgcn_readfirstlane(Q1.x);            \
    U[5] = (unsigned)__builtin_amdgcn_readfirstlane(Q1.y);            \
    U[6] = (unsigned)__builtin_amdgcn_readfirstlane(Q1.z);            \
    U[7] = (unsigned)__builtin_amdgcn_readfirstlane(Q1.w);

    {   // fwd stream: T1 += s2(Apb + D_j)
        const unsigned short* L = sFwd[w];
        int c = 0;
        for (; c + 16 <= mf; c += 16) {
            int4 q0 = *(const int4*)(L + c);
            int4 q1 = *(const int4*)(L + c + 8);
            UNPACK8(q0, q1, u)
            float d[16];
#pragma unroll
            for (int k = 0; k < 8; ++k) {     // 16 independent gathers in flight
                d[2 * k]     = baseD[((size_t)(u[k] & 0xffffu) << 6) + h];
                d[2 * k + 1] = baseD[((size_t)(u[k] >> 16) << 6) + h];
            }
#pragma unroll
            for (int k = 0; k < 16; ++k) T1 += s2core(Apb + d[k]);
        }
        for (; c + 8 <= mf; c += 8) {
            int4 q0 = *(const int4*)(L + c);
            int4 q1 = q0;
            UNPACK8(q0, q1, u)
            float d[8];
#pragma unroll
            for (int k = 0; k < 4; ++k) {
                d[2 * k]     = baseD[((size_t)(u[k] & 0xffffu) << 6) + h];
                d[2 * k + 1] = baseD[((size_t)(u[k] >> 16) << 6) + h];
            }
#pragma unroll
            for (int k = 0; k < 8; ++k) T1 += s2core(Apb + d[k]);
        }
        for (; c < mf; ++c) {
            unsigned jl = (unsigned)__builtin_amdgcn_readfirstlane((int)L[c]);
            T1 += s2core(Apb + baseD[((size_t)jl << 6) + h]);
        }
    }
    {   // rev stream: T2 += s2(Dpb + A_j)
        const unsigned short* L = sRev[w];
        int c = 0;
        for (; c + 16 <= mr; c += 16) {
            int4 q0 = *(const int4*)(L + c);
            int4 q1 = *(const int4*)(L + c + 8);
            UNPACK8(q0, q1, u)
            float d[16];
#pragma unroll
            for (int k = 0; k < 8; ++k) {
                d[2 * k]     = baseA[((size_t)(u[k] & 0xffffu) << 6) + h];
                d[2 * k + 1] = baseA[((size_t)(u[k] >> 16) << 6) + h];
            }
#pragma unroll
            for (int k = 0; k < 16; ++k) T2 += s2core(Dpb + d[k]);
        }
        for (; c + 8 <= mr; c += 8) {
            int4 q0 = *(const int4*)(L + c);
            int4 q1 = q0;
            UNPACK8(q0, q1, u)
            float d[8];
#pragma unroll
            for (int k = 0; k < 4; ++k) {
                d[2 * k]     = baseA[((size_t)(u[k] & 0xffffu) << 6) + h];
                d[2 * k + 1] = baseA[((size_t)(u[k] >> 16) << 6) + h];
            }
#pragma unroll
            for (int k = 0; k < 8; ++k) T2 += s2core(Dpb + d[k]);
        }
        for (; c < mr; ++c) {
            unsigned jl = (unsigned)__builtin_amdgcn_readfirstlane((int)L[c]);
            T2 += s2core(Dpb + baseA[((size_t)jl << 6) + h]);
        }
    }
#undef UNPACK8

    sS[w][h] = vh4 * T1;
    sS[w][64 + h] = vh4 * T2;
    __threadfence_block();                    // wave-local: no block barrier needed

    float g = 0.f;
    if (h < 32) {                             // l<16: W1_top@S1 ; 16<=l<32: W1_bot@S2
        const float* Sv = &sS[w][(h < 16) ? 0 : 64];
        float a0 = 0.f, a1 = 0.f, a2 = 0.f, a3 = 0.f;   // 4-way ILP fma chains
        for (int hh = 0; hh < 64; hh += 4) {
            a0 = fmaf(sW1t[(hh + 0) * 33 + h], Sv[hh + 0], a0);
            a1 = fmaf(sW1t[(hh + 1) * 33 + h], Sv[hh + 1], a1);
            a2 = fmaf(sW1t[(hh + 2) * 33 + h], Sv[hh + 2], a2);
            a3 = fmaf(sW1t[(hh + 3) * 33 + h], Sv[hh + 3], a3);
        }
        g = (a0 + a1) + (a2 + a3);
    }
    float g2 = __shfl(g, (h + 16) & 63);
    if (h < DD) {
        float xn = x[(size_t)p * DD + h] - DT_C * (g + g2);
        xOut[(size_t)p * DD + h] = xn;
        if (h < 2) posOut[p * 2 + h] = xn;
    }
}

extern "C" void kernel_launch(void* const* d_in, const int* in_sizes, int n_in,
                              void* d_out, int out_size, void* d_ws, size_t ws_size,
                              hipStream_t stream) {
    const float* x0   = (const float*)d_in[0];
    const float* W1   = (const float*)d_in[1];
    const float* b1   = (const float*)d_in[2];
    const float* W2   = (const float*)d_in[3];
    const float* Wout = (const float*)d_in[5];
    float* out = (float*)d_out;

    // workspace layout (floats); total ~24 MB
    float* ws   = (float*)d_ws;
    float* posA = ws;                        // 32768 (dead sink for last step)
    float* posB = posA + 32768;              // 32768
    float* x1   = posB + 32768;              // 262144
    float* Apl  = x1 + 262144;               // 16384*64 (4 MB)
    float* Dpl  = Apl + 16384 * 64;          // 16384*64 (4 MB)
    float* cut  = Dpl + 16384 * 64;          // 16384
    int*   cnt  = (int*)(cut + 16384);       // 16384
    float2* cand = (float2*)(cnt + 16384);   // 16384*96 float2 (12.6 MB)
    unsigned short* fwd = (unsigned short*)(cand + (size_t)16384 * CAP);  // 16384*48
    float2* sPosS = (float2*)(fwd + (size_t)16384 * FCAP);                // 16384 float2
    unsigned short* sIdx = (unsigned short*)(sPosS + 16384);              // 16384
    int* bandStart = (int*)(sIdx + 16384);                                // 8*32
    float* vArr = (float*)(bandStart + 8 * 32);                           // 64

    const int NB = (BB * NN) / WPB;          // 2048 blocks x 512 thr

    // step 0: x0 -> x1
    k_bin<true><<<BB, 1024, 0, stream>>>(x0, nullptr, W2, Wout, sPosS, sIdx,
                                         bandStart, vArr);
    k_neighbors<<<NB, BLOCK, 0, stream>>>(x0, sPosS, sIdx, bandStart, W1,
                                          cand, fwd, cnt, cut, Apl, Dpl);
    k_grad<<<NB, BLOCK, 0, stream>>>(x0, cut, cnt, cand, fwd, Apl, Dpl,
                                     W1, b1, vArr, x1, posB);
    // step 1: x1 -> out
    k_bin<false><<<BB, 1024, 0, stream>>>(nullptr, posB, W2, Wout, sPosS, sIdx,
                                          bandStart, vArr);
    k_neighbors<<<NB, BLOCK, 0, stream>>>(x1, sPosS, sIdx, bandStart, W1,
                                          cand, fwd, cnt, cut, Apl, Dpl);
    k_grad<<<NB, BLOCK, 0, stream>>>(x1, cut, cnt, cand, fwd, Apl, Dpl,
                                     W1, b1, vArr, out, posA);
}

// Round 9
// 167.353 us; speedup vs baseline: 1.0199x; 1.0199x over previous
//
#include <hip/hip_runtime.h>
#include <cstdint>
#include <cstddef>

// Problem constants (from reference setup_inputs)
#define BB   8
#define NN   2048
#define DD   16
#define HHH  64
#define KK   32
#define CAP  96          // max within-R hits kept incl self (mean ~37, Poisson tail safe)
#define FCAP 48          // max fwd neighbors kept (<=32 barring exact d2 ties)
#define DT_C 0.01f
#define R2_C (0.08f * 0.08f)
#define CEXP (-2.885390081777927f)   // -2*log2(e):  exp(-2|z|) = exp2(CEXP*|z|)

// 2-D cell grid: 17x17 cells of size R, covering [-0.68, 0.68]^2 (clamped edges)
#define GRID 17
#define NCEL (GRID * GRID)           // 289
#define GOFF 0.68f
#define CINV 12.5f                   // 1/R
#define CSTRIDE 320                  // ints per batch in cellStart

#define WPB   8                 // waves per block (1 particle per wave)
#define BLOCK (WPB * 64)

// Same rounding as the reference's sum-of-squares (sub,sub,mul,mul,add; no fma).
__device__ __forceinline__ float dist2(float px, float py, float qx, float qy) {
    float dx = __fsub_rn(px, qx);
    float dy = __fsub_rn(py, qy);
    return __fadd_rn(__fmul_rn(dx, dx), __fmul_rn(dy, dy));
}

// v_mbcnt_lo/hi natively count set bits among lanes BELOW the caller: prefix count.
__device__ __forceinline__ int prefix_cnt(unsigned long long m) {
    return (int)__builtin_amdgcn_mbcnt_hi(
        (unsigned)(m >> 32), __builtin_amdgcn_mbcnt_lo((unsigned)m, 0u));
}

// batch = blk&7 (XCD-aware), slot = consecutive sorted slots per block (L1 locality).
__device__ __forceinline__ int swizzled_slot(int blk, int w, int& bbase) {
    bbase = (blk & 7) << 11;
    return (blk >> 3) * WPB + w;     // batch-local sorted slot
}

__device__ __forceinline__ int clampi(int v, int lo, int hi) {
    return v < lo ? lo : (v > hi ? hi : v);
}

// Per step, one block per batch: counting-sort particles into 17x17 R-cells.
// sortedPos entries are verbatim bit-copies -> d2 values unchanged.
// Block 0 additionally computes v = W2 @ Wout once for the whole step.
template <bool FIRST>
__global__ __launch_bounds__(1024) void k_bin(
    const float* __restrict__ x, const float* __restrict__ pos,
    const float* __restrict__ W2, const float* __restrict__ Wout,
    float2* __restrict__ sortedPos, unsigned short* __restrict__ sortedIdx,
    int* __restrict__ cellStart, float* __restrict__ vOut) {
    __shared__ int hist[NCEL], base[NCEL + 1], cursor[NCEL];
    int bat = blockIdx.x, bbase = bat << 11, tid = threadIdx.x;
    if (tid < NCEL) hist[tid] = 0;
    if (blockIdx.x == 0 && tid >= 512 && tid < 512 + HHH) {   // v = W2 @ Wout
        int hh = tid - 512;
        float acc = 0.f;
        for (int c = 0; c < 32; c++) acc = fmaf(W2[hh * 32 + c], Wout[c], acc);
        vOut[hh] = acc;
    }
    __syncthreads();
    float2 q[2]; int cid[2];
#pragma unroll
    for (int u = 0; u < 2; ++u) {
        int i = tid + (u << 10);
        float2 qq = FIRST ? *(const float2*)(x + (size_t)(bbase + i) * DD)
                          : *(const float2*)(pos + (size_t)(bbase + i) * 2);
        q[u] = qq;
        int cx = clampi((int)((qq.x + GOFF) * CINV), 0, GRID - 1);
        int cy = clampi((int)((qq.y + GOFF) * CINV), 0, GRID - 1);
        cid[u] = cy * GRID + cx;
        atomicAdd(&hist[cid[u]], 1);
    }
    __syncthreads();
    if (tid < 64) {             // wave 0: exclusive prefix over 289 bins, 5/lane
        int loc[5], s = 0;
#pragma unroll
        for (int k = 0; k < 5; ++k) {
            int idx = tid * 5 + k;
            loc[k] = (idx < NCEL) ? hist[idx] : 0;
            s += loc[k];
        }
        int pre = s;
#pragma unroll
        for (int off = 1; off < 64; off <<= 1) {
            int t = __shfl_up(pre, off);
            if (tid >= off) pre += t;
        }
        pre -= s;               // exclusive prefix of this lane's first bin
#pragma unroll
        for (int k = 0; k < 5; ++k) {
            int idx = tid * 5 + k;
            if (idx <= NCEL) base[idx] = pre;
            pre += loc[k];
        }
    }
    __syncthreads();
    if (tid < NCEL) cursor[tid] = base[tid];
    if (tid <= NCEL) cellStart[bat * CSTRIDE + tid] = base[tid];
    __syncthreads();
#pragma unroll
    for (int u = 0; u < 2; ++u) {
        int dst = atomicAdd(&cursor[cid[u]], 1);
        sortedPos[bbase + dst] = q[u];
        sortedIdx[bbase + dst] = (unsigned short)(tid + (u << 10));
    }
}

// Kernel 1 per step, one wave per SORTED slot s — barrier-free:
//  - A/D precompute for the particle, stored at sorted slot
//  - scan the 3x3 cell window (~104 candidates, 3 contiguous sorted ranges)
//  - cutoff = rank-KK value incl self (bitonic; LDS rank-select if cnt>64)
//  - emit candList {d2, sorted j} + pre-compacted fwd u16 list (self dropped)
__global__ __launch_bounds__(BLOCK) void k_neighbors(
    const float* __restrict__ x,
    const float2* __restrict__ sortedPos, const unsigned short* __restrict__ sortedIdx,
    const int* __restrict__ cellStart, const float* __restrict__ W1,
    float2* __restrict__ candList, unsigned short* __restrict__ fwdList,
    int* __restrict__ cntArr, float* __restrict__ cutArr,
    float* __restrict__ Aplane, float* __restrict__ Dplane) {
    __shared__ float2 sDJ[WPB][CAP];        // 6 KB; wave-private

    int tid = threadIdx.x;
    int w = tid >> 6, lane = tid & 63;
    int bbase;
    int s = swizzled_slot(blockIdx.x, w, bbase);
    int bat = bbase >> 11;
    int gs = bbase + s;                     // global sorted slot

    // ---- A/D precompute (lane = h); W1 direct from global (cache-hot) ----
    int jol = (int)sortedIdx[gs];           // original batch-local id (wave-uniform)
    const float* xrow = x + (size_t)(bbase + jol) * DD;
    float xv = (lane < DD) ? xrow[lane] : 0.f;
    float px = __shfl(xv, 0), py = __shfl(xv, 1);
    float A = 0.f, Dv = 0.f;
#pragma unroll
    for (int f = 0; f < DD; f++) {
        float xf = __shfl(xv, f);
        A  = fmaf(xf, W1[f * HHH + lane], A);
        Dv = fmaf(xf, W1[(DD + f) * HHH + lane], Dv);
    }
    Aplane[((size_t)gs << 6) + lane] = A;
    Dplane[((size_t)gs << 6) + lane] = Dv;

    // ---- 3x3 cell window: three contiguous sorted ranges ----
    const int* CS = cellStart + bat * CSTRIDE;
    int cx = clampi((int)((px + GOFF) * CINV), 0, GRID - 1);
    int cy = clampi((int)((py + GOFF) * CINV), 0, GRID - 1);
    int xlo = cx > 0 ? cx - 1 : 0;
    int xhi = cx < GRID - 1 ? cx + 1 : GRID - 1;
    int rs0 = 0, rl0 = 0, rs1 = 0, rl1 = 0, rs2 = 0, rl2 = 0;
    if (cy > 0) {
        int a = CS[(cy - 1) * GRID + xlo], b = CS[(cy - 1) * GRID + xhi + 1];
        rs0 = a; rl0 = b - a;
    }
    {
        int a = CS[cy * GRID + xlo], b = CS[cy * GRID + xhi + 1];
        rs1 = a; rl1 = b - a;
    }
    if (cy < GRID - 1) {
        int a = CS[(cy + 1) * GRID + xlo], b = CS[(cy + 1) * GRID + xhi + 1];
        rs2 = a; rl2 = b - a;
    }
    int tot = rl0 + rl1 + rl2;

    // ---- candidate scan (self included: d2 == 0 exactly) ----
    int cnt = 0;
    for (int c0 = 0; c0 < tot; c0 += 64) {
        int t = c0 + lane;
        int j = rs0 + t;
        int u1 = t - rl0;
        if (u1 >= 0) j = rs1 + u1;
        int u2 = u1 - rl1;
        if (u2 >= 0) j = rs2 + u2;
        bool in = t < tot;
        float2 q = sortedPos[bbase + (in ? j : 0)];
        float d2 = dist2(px, py, q.x, q.y);
        bool hit = in && (d2 < R2_C);
        unsigned long long m = __ballot(hit);
        int idx = cnt + prefix_cnt(m);
        if (hit && idx < CAP)
            sDJ[w][idx] = make_float2(d2, __uint_as_float((unsigned)j));
        cnt += (int)__popcll(m);
    }
    if (cnt > CAP) cnt = CAP;
    __threadfence_block();   // wave-local LDS RAW drain

    // ---- cutoff = rank-KK value (0-based, incl self) ----
    float cutoff = R2_C;
    if (cnt > KK + 1) {
        const float INF = 1e30f;
        if (cnt <= 64) {
            float v = (lane < cnt) ? sDJ[w][lane].x : INF;
#pragma unroll
            for (int k = 2; k <= 64; k <<= 1) {
#pragma unroll
                for (int j = k >> 1; j > 0; j >>= 1) {
                    float pv = __shfl_xor(v, j);
                    bool up = ((lane & k) == 0);
                    bool takeMin = (((lane & j) == 0) == up);
                    v = takeMin ? fminf(v, pv) : fmaxf(v, pv);
                }
            }
            cutoff = __shfl(v, KK);       // ascending; rank shifted by self
        } else {                          // cnt in (64,96]: ~never, kept for correctness
            float e0 = (lane < cnt) ? sDJ[w][lane].x : INF;
            float e1 = (lane + 64 < cnt) ? sDJ[w][lane + 64].x : INF;
            int r0 = 0, q0 = 0, r1 = 0, q1 = 0;
            for (int k = 0; k < cnt; k++) {
                float val = sDJ[w][k].x;
                r0 += (val < e0); q0 += (val == e0);
                r1 += (val < e1); q1 += (val == e1);
            }
            bool c0 = (r0 <= KK) && (r0 + q0 > KK);
            bool c1 = (r1 <= KK) && (r1 + q1 > KK);
            float cand = c0 ? e0 : (c1 ? e1 : INF);
#pragma unroll
            for (int off = 32; off; off >>= 1) cand = fminf(cand, __shfl_xor(cand, off));
            cutoff = cand;
        }
    }

    // ---- emission (sorted ids throughout; self dropped by slot compare) ----
    int me = 0, mf = 0;
    for (int c0 = 0; c0 < cnt; c0 += 64) {
        int c = c0 + lane;
        bool act = c < cnt;
        float2 e = sDJ[w][act ? c : 0];
        unsigned js = __float_as_uint(e.y);
        bool keep = act && ((int)js != s);
        unsigned long long mK = __ballot(keep);
        int ie = me + prefix_cnt(mK);
        if (keep) candList[(size_t)gs * CAP + ie] = e;
        me += (int)__popcll(mK);
        bool fw = keep && (e.x <= cutoff);
        unsigned long long mF = __ballot(fw);
        int iF = mf + prefix_cnt(mF);
        if (fw && iF < FCAP) fwdList[(size_t)gs * FCAP + iF] = (unsigned short)js;
        mf += (int)__popcll(mF);
    }
    if (mf > FCAP) mf = FCAP;
    if (lane == 0) { cutArr[gs] = cutoff; cntArr[gs] = me | (mf << 16); }
}

// Kernel 2 per step, one wave per SORTED slot s (lane = h). Consecutive slots
// per block -> neighbor rows spatially clustered -> L1-resident gathers.
__global__ __launch_bounds__(BLOCK) void k_grad(
    const float* __restrict__ x, const unsigned short* __restrict__ sortedIdx,
    const float* __restrict__ cutArr, const int* __restrict__ cntArr,
    const float2* __restrict__ candList, const unsigned short* __restrict__ fwdList,
    const float* __restrict__ Aplane, const float* __restrict__ Dplane,
    const float* __restrict__ W1, const float* __restrict__ b1,
    const float* __restrict__ vArr,
    float* __restrict__ xOut, float* __restrict__ posOut) {
    __shared__ float sW1t[HHH * 33];                       // 8.25 KB
    __shared__ alignas(16) unsigned short sFwd[WPB][FCAP]; // 768 B
    __shared__ alignas(16) unsigned short sRev[WPB][CAP];  // 1.5 KB
    __shared__ float sS[WPB][128];                         // 4 KB (~14.5 KB total)

    int tid = threadIdx.x;
    int w = tid >> 6, h = tid & 63;
    int bbase;
    int s = swizzled_slot(blockIdx.x, w, bbase);
    int gs = bbase + s;

    for (int t = tid; t < 2 * DD * HHH; t += BLOCK) {
        int f = t >> 6, hh = t & 63;
        sW1t[hh * 33 + f] = W1[t];            // pad 33: conflict-free write & read
    }
    __syncthreads();                          // the only block barrier

    float b1h = b1[h];
    float Apb = Aplane[((size_t)gs << 6) + h] + b1h;
    float Dpb = Dplane[((size_t)gs << 6) + h] + b1h;
    float vh4 = 4.f * vArr[h];                // precomputed in k_bin (L2-hot)
    int packed = cntArr[gs];
    int cnt = packed & 0xffff;
    int mf = packed >> 16;

    // stage fwd list: one guarded coalesced copy (k1 already compacted it)
    if (h < mf) sFwd[w][h] = fwdList[(size_t)gs * FCAP + h];

    // ---- rev prepass: stored d2 vs cut[j] gather, ballot-compact ----
    int mr = 0;
    for (int c0 = 0; c0 < cnt; c0 += 64) {
        int c = c0 + h;
        bool act = c < cnt;
        float2 e = candList[(size_t)gs * CAP + (act ? c : 0)];
        unsigned jl = __float_as_uint(e.y) & (NN - 1);
        bool rev = act && (e.x <= cutArr[bbase + jl]);
        unsigned long long mR = __ballot(rev);
        int iR = mr + prefix_cnt(mR);
        if (rev) sRev[w][iR] = (unsigned short)jl;
        mr += (int)__popcll(mR);
    }
    __threadfence_block();

    // ---- main loops: branch-free, 16-deep gather batching, scalar-decoded ----
    const float* baseD = Dplane + ((size_t)bbase << 6);
    const float* baseA = Aplane + ((size_t)bbase << 6);
    float T1 = 0.f, T2 = 0.f;

    auto s2core = [&](float z) {
        float a = __builtin_amdgcn_exp2f(CEXP * fabsf(z));
        float bb = 1.f + a;
        return a * __builtin_amdgcn_rcpf(bb * bb);
    };

#define UNPACK8(Q0, Q1, U)                                            \
    unsigned U[8];                                                    \
    U[0] = (unsigned)__builtin_amdgcn_readfirstlane(Q0.x);            \
    U[1] = (unsigned)__builtin_amdgcn_readfirstlane(Q0.y);            \
    U[2] = (unsigned)__builtin_amdgcn_readfirstlane(Q0.z);            \
    U[3] = (unsigned)__builtin_amdgcn_readfirstlane(Q0.w);            \
    U[4] = (unsigned)__builtin_amdgcn_readfirstlane(Q1.x);            \
    U[5] = (unsigned)__builtin_amdgcn_readfirstlane(Q1.y);            \
    U[6] = (unsigned)__builtin_amdgcn_readfirstlane(Q1.z);            \
    U[7] = (unsigned)__builtin_amdgcn_readfirstlane(Q1.w);

    {   // fwd stream: T1 += s2(Apb + D_j)
        const unsigned short* L = sFwd[w];
        int c = 0;
        for (; c + 16 <= mf; c += 16) {
            int4 q0 = *(const int4*)(L + c);
            int4 q1 = *(const int4*)(L + c + 8);
            UNPACK8(q0, q1, u)
            float d[16];
#pragma unroll
            for (int k = 0; k < 8; ++k) {     // 16 independent gathers in flight
                d[2 * k]     = baseD[((size_t)(u[k] & 0xffffu) << 6) + h];
                d[2 * k + 1] = baseD[((size_t)(u[k] >> 16) << 6) + h];
            }
#pragma unroll
            for (int k = 0; k < 16; ++k) T1 += s2core(Apb + d[k]);
        }
        for (; c + 8 <= mf; c += 8) {
            int4 q0 = *(const int4*)(L + c);
            int4 q1 = q0;
            UNPACK8(q0, q1, u)
            float d[8];
#pragma unroll
            for (int k = 0; k < 4; ++k) {
                d[2 * k]     = baseD[((size_t)(u[k] & 0xffffu) << 6) + h];
                d[2 * k + 1] = baseD[((size_t)(u[k] >> 16) << 6) + h];
            }
#pragma unroll
            for (int k = 0; k < 8; ++k) T1 += s2core(Apb + d[k]);
        }
        for (; c < mf; ++c) {
            unsigned jl = (unsigned)__builtin_amdgcn_readfirstlane((int)L[c]);
            T1 += s2core(Apb + baseD[((size_t)jl << 6) + h]);
        }
    }
    {   // rev stream: T2 += s2(Dpb + A_j)
        const unsigned short* L = sRev[w];
        int c = 0;
        for (; c + 16 <= mr; c += 16) {
            int4 q0 = *(const int4*)(L + c);
            int4 q1 = *(const int4*)(L + c + 8);
            UNPACK8(q0, q1, u)
            float d[16];
#pragma unroll
            for (int k = 0; k < 8; ++k) {
                d[2 * k]     = baseA[((size_t)(u[k] & 0xffffu) << 6) + h];
                d[2 * k + 1] = baseA[((size_t)(u[k] >> 16) << 6) + h];
            }
#pragma unroll
            for (int k = 0; k < 16; ++k) T2 += s2core(Dpb + d[k]);
        }
        for (; c + 8 <= mr; c += 8) {
            int4 q0 = *(const int4*)(L + c);
            int4 q1 = q0;
            UNPACK8(q0, q1, u)
            float d[8];
#pragma unroll
            for (int k = 0; k < 4; ++k) {
                d[2 * k]     = baseA[((size_t)(u[k] & 0xffffu) << 6) + h];
                d[2 * k + 1] = baseA[((size_t)(u[k] >> 16) << 6) + h];
            }
#pragma unroll
            for (int k = 0; k < 8; ++k) T2 += s2core(Dpb + d[k]);
        }
        for (; c < mr; ++c) {
            unsigned jl = (unsigned)__builtin_amdgcn_readfirstlane((int)L[c]);
            T2 += s2core(Dpb + baseA[((size_t)jl << 6) + h]);
        }
    }
#undef UNPACK8

    sS[w][h] = vh4 * T1;
    sS[w][64 + h] = vh4 * T2;
    __threadfence_block();                    // wave-local: no block barrier needed

    float g = 0.f;
    if (h < 32) {                             // l<16: W1_top@S1 ; 16<=l<32: W1_bot@S2
        const float* Sv = &sS[w][(h < 16) ? 0 : 64];
        float a0 = 0.f, a1 = 0.f, a2 = 0.f, a3 = 0.f;   // 4-way ILP fma chains
        for (int hh = 0; hh < 64; hh += 4) {
            a0 = fmaf(sW1t[(hh + 0) * 33 + h], Sv[hh + 0], a0);
            a1 = fmaf(sW1t[(hh + 1) * 33 + h], Sv[hh + 1], a1);
            a2 = fmaf(sW1t[(hh + 2) * 33 + h], Sv[hh + 2], a2);
            a3 = fmaf(sW1t[(hh + 3) * 33 + h], Sv[hh + 3], a3);
        }
        g = (a0 + a1) + (a2 + a3);
    }
    float g2 = __shfl(g, (h + 16) & 63);
    int jo = (int)sortedIdx[gs];              // original batch-local id (uniform)
    if (h < DD) {
        size_t prow = (size_t)(bbase + jo) * DD;
        float xn = x[prow + h] - DT_C * (g + g2);
        xOut[prow + h] = xn;
        if (h < 2) posOut[(bbase + jo) * 2 + h] = xn;
    }
}

extern "C" void kernel_launch(void* const* d_in, const int* in_sizes, int n_in,
                              void* d_out, int out_size, void* d_ws, size_t ws_size,
                              hipStream_t stream) {
    const float* x0   = (const float*)d_in[0];
    const float* W1   = (const float*)d_in[1];
    const float* b1   = (const float*)d_in[2];
    const float* W2   = (const float*)d_in[3];
    const float* Wout = (const float*)d_in[5];
    float* out = (float*)d_out;

    // workspace layout (floats); total ~24 MB
    float* ws   = (float*)d_ws;
    float* posA = ws;                        // 32768 (dead sink for last step)
    float* posB = posA + 32768;              // 32768
    float* x1   = posB + 32768;              // 262144
    float* Apl  = x1 + 262144;               // 16384*64 (4 MB)
    float* Dpl  = Apl + 16384 * 64;          // 16384*64 (4 MB)
    float* cut  = Dpl + 16384 * 64;          // 16384
    int*   cnt  = (int*)(cut + 16384);       // 16384
    float2* cand = (float2*)(cnt + 16384);   // 16384*96 float2 (12.6 MB)
    unsigned short* fwd = (unsigned short*)(cand + (size_t)16384 * CAP);  // 16384*48
    float2* sPosS = (float2*)(fwd + (size_t)16384 * FCAP);                // 16384 float2
    unsigned short* sIdx = (unsigned short*)(sPosS + 16384);              // 16384
    int* cellStart = (int*)(sIdx + 16384);                                // 8*320
    float* vArr = (float*)(cellStart + BB * CSTRIDE);                     // 64

    const int NB = (BB * NN) / WPB;          // 2048 blocks x 512 thr

    // step 0: x0 -> x1
    k_bin<true><<<BB, 1024, 0, stream>>>(x0, nullptr, W2, Wout, sPosS, sIdx,
                                         cellStart, vArr);
    k_neighbors<<<NB, BLOCK, 0, stream>>>(x0, sPosS, sIdx, cellStart, W1,
                                          cand, fwd, cnt, cut, Apl, Dpl);
    k_grad<<<NB, BLOCK, 0, stream>>>(x0, sIdx, cut, cnt, cand, fwd, Apl, Dpl,
                                     W1, b1, vArr, x1, posB);
    // step 1: x1 -> out
    k_bin<false><<<BB, 1024, 0, stream>>>(nullptr, posB, W2, Wout, sPosS, sIdx,
                                          cellStart, vArr);
    k_neighbors<<<NB, BLOCK, 0, stream>>>(x1, sPosS, sIdx, cellStart, W1,
                                          cand, fwd, cnt, cut, Apl, Dpl);
    k_grad<<<NB, BLOCK, 0, stream>>>(x1, sIdx, cut, cnt, cand, fwd, Apl, Dpl,
                                     W1, b1, vArr, out, posA);
}

// Round 10
// 159.406 us; speedup vs baseline: 1.0707x; 1.0499x over previous
//
#include <hip/hip_runtime.h>
#include <cstdint>
#include <cstddef>

// Problem constants (from reference setup_inputs)
#define BB   8
#define NN   2048
#define DD   16
#define HHH  64
#define KK   32
#define CAP  96          // max within-R hits kept incl self (mean ~37, Poisson tail safe)
#define FCAP 48          // max fwd neighbors kept (<=32 barring exact d2 ties)
#define DT_C 0.01f
#define R2_C (0.08f * 0.08f)
#define CEXP (-2.885390081777927f)   // -2*log2(e):  exp(-2|z|) = exp2(-|CEXP*z|), CEXP<0

// 2-D cell grid: 17x17 cells of size R, covering [-0.68, 0.68]^2 (clamped edges)
#define GRID 17
#define NCEL (GRID * GRID)           // 289
#define GOFF 0.68f
#define CINV 12.5f                   // 1/R
#define CSTRIDE 320                  // ints per batch in cellStart

#define WPB   8                 // waves per block (1 particle per wave)
#define BLOCK (WPB * 64)

// Same rounding as the reference's sum-of-squares (sub,sub,mul,mul,add; no fma).
__device__ __forceinline__ float dist2(float px, float py, float qx, float qy) {
    float dx = __fsub_rn(px, qx);
    float dy = __fsub_rn(py, qy);
    return __fadd_rn(__fmul_rn(dx, dx), __fmul_rn(dy, dy));
}

// v_mbcnt_lo/hi natively count set bits among lanes BELOW the caller: prefix count.
__device__ __forceinline__ int prefix_cnt(unsigned long long m) {
    return (int)__builtin_amdgcn_mbcnt_hi(
        (unsigned)(m >> 32), __builtin_amdgcn_mbcnt_lo((unsigned)m, 0u));
}

// batch = blk&7 (XCD-aware), slot = consecutive sorted slots per block (L1 locality).
__device__ __forceinline__ int swizzled_slot(int blk, int w, int& bbase) {
    bbase = (blk & 7) << 11;
    return (blk >> 3) * WPB + w;     // batch-local sorted slot
}

__device__ __forceinline__ int clampi(int v, int lo, int hi) {
    return v < lo ? lo : (v > hi ? hi : v);
}

// 3x3 cell window of (px,py): three contiguous sorted ranges. Shared by k_cut/k_grad.
struct Win { int rs0, rl0, rs1, rl1, rs2, rl2, tot; };
__device__ __forceinline__ Win cell_window(const int* CS, float px, float py) {
    Win W;
    int cx = clampi((int)((px + GOFF) * CINV), 0, GRID - 1);
    int cy = clampi((int)((py + GOFF) * CINV), 0, GRID - 1);
    int xlo = cx > 0 ? cx - 1 : 0;
    int xhi = cx < GRID - 1 ? cx + 1 : GRID - 1;
    W.rs0 = 0; W.rl0 = 0; W.rs2 = 0; W.rl2 = 0;
    if (cy > 0) {
        int a = CS[(cy - 1) * GRID + xlo], b = CS[(cy - 1) * GRID + xhi + 1];
        W.rs0 = a; W.rl0 = b - a;
    }
    {
        int a = CS[cy * GRID + xlo], b = CS[cy * GRID + xhi + 1];
        W.rs1 = a; W.rl1 = b - a;
    }
    if (cy < GRID - 1) {
        int a = CS[(cy + 1) * GRID + xlo], b = CS[(cy + 1) * GRID + xhi + 1];
        W.rs2 = a; W.rl2 = b - a;
    }
    W.tot = W.rl0 + W.rl1 + W.rl2;
    return W;
}
__device__ __forceinline__ int win_map(const Win& W, int t) {
    int j = W.rs0 + t;
    int u1 = t - W.rl0;
    if (u1 >= 0) j = W.rs1 + u1;
    int u2 = u1 - W.rl1;
    if (u2 >= 0) j = W.rs2 + u2;
    return j;
}

// Per step, one block per batch: counting-sort particles into 17x17 R-cells.
// sortedPos entries are verbatim bit-copies -> d2 values unchanged.
// Block 0 additionally computes v = W2 @ Wout once for the whole step.
template <bool FIRST>
__global__ __launch_bounds__(1024) void k_bin(
    const float* __restrict__ x, const float* __restrict__ pos,
    const float* __restrict__ W2, const float* __restrict__ Wout,
    float2* __restrict__ sortedPos, unsigned short* __restrict__ sortedIdx,
    int* __restrict__ cellStart, float* __restrict__ vOut) {
    __shared__ int hist[NCEL], base[NCEL + 1], cursor[NCEL];
    int bat = blockIdx.x, bbase = bat << 11, tid = threadIdx.x;
    if (tid < NCEL) hist[tid] = 0;
    if (blockIdx.x == 0 && tid >= 512 && tid < 512 + HHH) {   // v = W2 @ Wout
        int hh = tid - 512;
        float acc = 0.f;
        for (int c = 0; c < 32; c++) acc = fmaf(W2[hh * 32 + c], Wout[c], acc);
        vOut[hh] = acc;
    }
    __syncthreads();
    float2 q[2]; int cid[2];
#pragma unroll
    for (int u = 0; u < 2; ++u) {
        int i = tid + (u << 10);
        float2 qq = FIRST ? *(const float2*)(x + (size_t)(bbase + i) * DD)
                          : *(const float2*)(pos + (size_t)(bbase + i) * 2);
        q[u] = qq;
        int cx = clampi((int)((qq.x + GOFF) * CINV), 0, GRID - 1);
        int cy = clampi((int)((qq.y + GOFF) * CINV), 0, GRID - 1);
        cid[u] = cy * GRID + cx;
        atomicAdd(&hist[cid[u]], 1);
    }
    __syncthreads();
    if (tid < 64) {             // wave 0: exclusive prefix over 289 bins, 5/lane
        int loc[5], s = 0;
#pragma unroll
        for (int k = 0; k < 5; ++k) {
            int idx = tid * 5 + k;
            loc[k] = (idx < NCEL) ? hist[idx] : 0;
            s += loc[k];
        }
        int pre = s;
#pragma unroll
        for (int off = 1; off < 64; off <<= 1) {
            int t = __shfl_up(pre, off);
            if (tid >= off) pre += t;
        }
        pre -= s;               // exclusive prefix of this lane's first bin
#pragma unroll
        for (int k = 0; k < 5; ++k) {
            int idx = tid * 5 + k;
            if (idx <= NCEL) base[idx] = pre;
            pre += loc[k];
        }
    }
    __syncthreads();
    if (tid < NCEL) cursor[tid] = base[tid];
    if (tid <= NCEL) cellStart[bat * CSTRIDE + tid] = base[tid];
    __syncthreads();
#pragma unroll
    for (int u = 0; u < 2; ++u) {
        int dst = atomicAdd(&cursor[cid[u]], 1);
        sortedPos[bbase + dst] = q[u];
        sortedIdx[bbase + dst] = (unsigned short)(tid + (u << 10));
    }
}

// Kernel 1 per step, one wave per SORTED slot s — barrier-free, cutoff-only:
//  - As = CEXP*(x @ W1[:16]), Ds = CEXP*(x @ W1[16:]) -> pre-scaled planes
//  - scan 3x3 cell window, collect hit d2's (self included, d2==0 exactly)
//  - cutoff = rank-KK value (0-based incl self); write cutArr[gs]. No emission.
__global__ __launch_bounds__(BLOCK) void k_cut(
    const float* __restrict__ x,
    const float2* __restrict__ sortedPos, const unsigned short* __restrict__ sortedIdx,
    const int* __restrict__ cellStart, const float* __restrict__ W1,
    float* __restrict__ cutArr,
    float* __restrict__ Asp, float* __restrict__ Dsp) {
    __shared__ float sD[WPB][CAP];          // 3 KB; wave-private hit d2's

    int tid = threadIdx.x;
    int w = tid >> 6, lane = tid & 63;
    int bbase;
    int s = swizzled_slot(blockIdx.x, w, bbase);
    int bat = bbase >> 11;
    int gs = bbase + s;                     // global sorted slot

    // ---- A/D precompute (lane = h); W1 direct from global (cache-hot) ----
    int jol = (int)sortedIdx[gs];           // original batch-local id (wave-uniform)
    const float* xrow = x + (size_t)(bbase + jol) * DD;
    float xv = (lane < DD) ? xrow[lane] : 0.f;
    float px = __shfl(xv, 0), py = __shfl(xv, 1);
    float A = 0.f, Dv = 0.f;
#pragma unroll
    for (int f = 0; f < DD; f++) {
        float xf = __shfl(xv, f);
        A  = fmaf(xf, W1[f * HHH + lane], A);
        Dv = fmaf(xf, W1[(DD + f) * HHH + lane], Dv);
    }
    Asp[((size_t)gs << 6) + lane] = CEXP * A;    // pre-scaled planes
    Dsp[((size_t)gs << 6) + lane] = CEXP * Dv;

    // ---- candidate scan over 3x3 window (self included) ----
    const int* CS = cellStart + bat * CSTRIDE;
    Win W = cell_window(CS, px, py);
    int cnt = 0;
    for (int c0 = 0; c0 < W.tot; c0 += 64) {
        int t = c0 + lane;
        int j = win_map(W, t);
        bool in = t < W.tot;
        float2 q = sortedPos[bbase + (in ? j : 0)];
        float d2 = dist2(px, py, q.x, q.y);
        bool hit = in && (d2 < R2_C);
        unsigned long long m = __ballot(hit);
        int idx = cnt + prefix_cnt(m);
        if (hit && idx < CAP) sD[w][idx] = d2;
        cnt += (int)__popcll(m);
    }
    if (cnt > CAP) cnt = CAP;
    __threadfence_block();   // wave-local LDS RAW drain

    // ---- cutoff = rank-KK value (0-based, incl self) ----
    float cutoff = R2_C;
    if (cnt > KK + 1) {
        const float INF = 1e30f;
        if (cnt <= 64) {
            float v = (lane < cnt) ? sD[w][lane] : INF;
#pragma unroll
            for (int k = 2; k <= 64; k <<= 1) {
#pragma unroll
                for (int j = k >> 1; j > 0; j >>= 1) {
                    float pv = __shfl_xor(v, j);
                    bool up = ((lane & k) == 0);
                    bool takeMin = (((lane & j) == 0) == up);
                    v = takeMin ? fminf(v, pv) : fmaxf(v, pv);
                }
            }
            cutoff = __shfl(v, KK);       // ascending; rank shifted by self
        } else {                          // cnt in (64,96]: ~never, kept for correctness
            float e0 = (lane < cnt) ? sD[w][lane] : INF;
            float e1 = (lane + 64 < cnt) ? sD[w][lane + 64] : INF;
            int r0 = 0, q0 = 0, r1 = 0, q1 = 0;
            for (int k = 0; k < cnt; k++) {
                float val = sD[w][k];
                r0 += (val < e0); q0 += (val == e0);
                r1 += (val < e1); q1 += (val == e1);
            }
            bool c0 = (r0 <= KK) && (r0 + q0 > KK);
            bool c1 = (r1 <= KK) && (r1 + q1 > KK);
            float cand = c0 ? e0 : (c1 ? e1 : INF);
#pragma unroll
            for (int off = 32; off; off >>= 1) cand = fminf(cand, __shfl_xor(cand, off));
            cutoff = cand;
        }
    }
    if (lane == 0) cutArr[gs] = cutoff;
}

// Kernel 2 per step, one wave per SORTED slot s (lane = h):
//  inline scan: d2 bit-identical; fwd = d2<=cut_p, rev = d2<=cut_j (self excl),
//  ballot-compact into LDS streams in scan order (order matches prior rounds).
//  main: T1 += s2(Apbs + Ds_j); T2 += s2(Dpbs + As_j); s2 via exp2(-|w|).
__global__ __launch_bounds__(BLOCK) void k_grad(
    const float* __restrict__ x, const unsigned short* __restrict__ sortedIdx,
    const float2* __restrict__ sortedPos, const int* __restrict__ cellStart,
    const float* __restrict__ cutArr,
    const float* __restrict__ Asp, const float* __restrict__ Dsp,
    const float* __restrict__ W1, const float* __restrict__ b1,
    const float* __restrict__ vArr,
    float* __restrict__ xOut, float* __restrict__ posOut) {
    __shared__ float sW1t[HHH * 33];                       // 8.25 KB
    __shared__ alignas(16) unsigned short sFwd[WPB][FCAP]; // 768 B
    __shared__ alignas(16) unsigned short sRev[WPB][CAP];  // 1.5 KB
    __shared__ float sS[WPB][128];                         // 4 KB (~14.5 KB total)

    int tid = threadIdx.x;
    int w = tid >> 6, h = tid & 63;
    int bbase;
    int s = swizzled_slot(blockIdx.x, w, bbase);
    int bat = bbase >> 11;
    int gs = bbase + s;

    for (int t = tid; t < 2 * DD * HHH; t += BLOCK) {
        int f = t >> 6, hh = t & 63;
        sW1t[hh * 33 + f] = W1[t];            // pad 33: conflict-free write & read
    }
    __syncthreads();                          // the only block barrier

    float b1s = CEXP * b1[h];
    float Apbs = Asp[((size_t)gs << 6) + h] + b1s;
    float Dpbs = Dsp[((size_t)gs << 6) + h] + b1s;
    float vh4 = 4.f * vArr[h];                // precomputed in k_bin (L2-hot)

    float2 pp = sortedPos[gs];                // verbatim copy of own position
    float px = pp.x, py = pp.y;
    float cutp = cutArr[gs];

    // ---- inline scan: flags from bit-identical d2/cut compares, compacted ----
    const int* CS = cellStart + bat * CSTRIDE;
    Win W = cell_window(CS, px, py);
    int mf = 0, mr = 0;
    for (int c0 = 0; c0 < W.tot; c0 += 64) {
        int t = c0 + h;
        int j = win_map(W, t);
        bool in = t < W.tot;
        int ja = in ? j : 0;
        float2 q = sortedPos[bbase + ja];
        float cutj = cutArr[bbase + ja];      // coalesced: j contiguous per range
        float d2 = dist2(px, py, q.x, q.y);   // bit-identical to k_cut
        bool hit = in && (d2 < R2_C) && (j != s);
        bool fw = hit && (d2 <= cutp);
        bool rv = hit && (d2 <= cutj);
        unsigned long long mF = __ballot(fw);
        int iF = mf + prefix_cnt(mF);
        if (fw && iF < FCAP) sFwd[w][iF] = (unsigned short)j;
        mf += (int)__popcll(mF);
        unsigned long long mR = __ballot(rv);
        int iR = mr + prefix_cnt(mR);
        if (rv && iR < CAP) sRev[w][iR] = (unsigned short)j;
        mr += (int)__popcll(mR);
    }
    if (mf > FCAP) mf = FCAP;
    if (mr > CAP) mr = CAP;
    __threadfence_block();

    // ---- main loops: branch-free, 16-deep gather batching, scalar row bases ----
    const float* baseD = Dsp + ((size_t)bbase << 6);
    const float* baseA = Asp + ((size_t)bbase << 6);
    float T1 = 0.f, T2 = 0.f;

    auto s2core = [&](float wz) {             // a = exp2(-|wz|): one trans w/ modifier
        float a = __builtin_amdgcn_exp2f(-fabsf(wz));
        float bb = 1.f + a;
        return a * __builtin_amdgcn_rcpf(bb * bb);
    };

#define UNPACK8(Q0, Q1, U)                                            \
    unsigned U[8];                                                    \
    U[0] = (unsigned)__builtin_amdgcn_readfirstlane(Q0.x);            \
    U[1] = (unsigned)__builtin_amdgcn_readfirstlane(Q0.y);            \
    U[2] = (unsigned)__builtin_amdgcn_readfirstlane(Q0.z);            \
    U[3] = (unsigned)__builtin_amdgcn_readfirstlane(Q0.w);            \
    U[4] = (unsigned)__builtin_amdgcn_readfirstlane(Q1.x);            \
    U[5] = (unsigned)__builtin_amdgcn_readfirstlane(Q1.y);            \
    U[6] = (unsigned)__builtin_amdgcn_readfirstlane(Q1.z);            \
    U[7] = (unsigned)__builtin_amdgcn_readfirstlane(Q1.w);

    {   // fwd stream: T1 += s2(Apbs + Ds_j)
        const unsigned short* L = sFwd[w];
        int c = 0;
        for (; c + 16 <= mf; c += 16) {
            int4 q0 = *(const int4*)(L + c);
            int4 q1 = *(const int4*)(L + c + 8);
            UNPACK8(q0, q1, u)
            float d[16];
#pragma unroll
            for (int k = 0; k < 8; ++k) {     // 16 independent gathers in flight
                const float* ra = baseD + ((size_t)(u[k] & 0xffffu) << 6);
                const float* rb = baseD + ((size_t)(u[k] >> 16) << 6);
                d[2 * k]     = ra[h];
                d[2 * k + 1] = rb[h];
            }
#pragma unroll
            for (int k = 0; k < 16; ++k) T1 += s2core(Apbs + d[k]);
        }
        for (; c + 8 <= mf; c += 8) {
            int4 q0 = *(const int4*)(L + c);
            int4 q1 = q0;
            UNPACK8(q0, q1, u)
            float d[8];
#pragma unroll
            for (int k = 0; k < 4; ++k) {
                const float* ra = baseD + ((size_t)(u[k] & 0xffffu) << 6);
                const float* rb = baseD + ((size_t)(u[k] >> 16) << 6);
                d[2 * k]     = ra[h];
                d[2 * k + 1] = rb[h];
            }
#pragma unroll
            for (int k = 0; k < 8; ++k) T1 += s2core(Apbs + d[k]);
        }
        for (; c < mf; ++c) {
            unsigned jl = (unsigned)__builtin_amdgcn_readfirstlane((int)L[c]);
            T1 += s2core(Apbs + (baseD + ((size_t)jl << 6))[h]);
        }
    }
    {   // rev stream: T2 += s2(Dpbs + As_j)
        const unsigned short* L = sRev[w];
        int c = 0;
        for (; c + 16 <= mr; c += 16) {
            int4 q0 = *(const int4*)(L + c);
            int4 q1 = *(const int4*)(L + c + 8);
            UNPACK8(q0, q1, u)
            float d[16];
#pragma unroll
            for (int k = 0; k < 8; ++k) {
                const float* ra = baseA + ((size_t)(u[k] & 0xffffu) << 6);
                const float* rb = baseA + ((size_t)(u[k] >> 16) << 6);
                d[2 * k]     = ra[h];
                d[2 * k + 1] = rb[h];
            }
#pragma unroll
            for (int k = 0; k < 16; ++k) T2 += s2core(Dpbs + d[k]);
        }
        for (; c + 8 <= mr; c += 8) {
            int4 q0 = *(const int4*)(L + c);
            int4 q1 = q0;
            UNPACK8(q0, q1, u)
            float d[8];
#pragma unroll
            for (int k = 0; k < 4; ++k) {
                const float* ra = baseA + ((size_t)(u[k] & 0xffffu) << 6);
                const float* rb = baseA + ((size_t)(u[k] >> 16) << 6);
                d[2 * k]     = ra[h];
                d[2 * k + 1] = rb[h];
            }
#pragma unroll
            for (int k = 0; k < 8; ++k) T2 += s2core(Dpbs + d[k]);
        }
        for (; c < mr; ++c) {
            unsigned jl = (unsigned)__builtin_amdgcn_readfirstlane((int)L[c]);
            T2 += s2core(Dpbs + (baseA + ((size_t)jl << 6))[h]);
        }
    }
#undef UNPACK8

    sS[w][h] = vh4 * T1;
    sS[w][64 + h] = vh4 * T2;
    __threadfence_block();                    // wave-local: no block barrier needed

    float g = 0.f;
    if (h < 32) {                             // l<16: W1_top@S1 ; 16<=l<32: W1_bot@S2
        const float* Sv = &sS[w][(h < 16) ? 0 : 64];
        float a0 = 0.f, a1 = 0.f, a2 = 0.f, a3 = 0.f;   // 4-way ILP fma chains
        for (int hh = 0; hh < 64; hh += 4) {
            a0 = fmaf(sW1t[(hh + 0) * 33 + h], Sv[hh + 0], a0);
            a1 = fmaf(sW1t[(hh + 1) * 33 + h], Sv[hh + 1], a1);
            a2 = fmaf(sW1t[(hh + 2) * 33 + h], Sv[hh + 2], a2);
            a3 = fmaf(sW1t[(hh + 3) * 33 + h], Sv[hh + 3], a3);
        }
        g = (a0 + a1) + (a2 + a3);
    }
    float g2 = __shfl(g, (h + 16) & 63);
    int jo = (int)sortedIdx[gs];              // original batch-local id (uniform)
    if (h < DD) {
        size_t prow = (size_t)(bbase + jo) * DD;
        float xn = x[prow + h] - DT_C * (g + g2);
        xOut[prow + h] = xn;
        if (h < 2) posOut[(bbase + jo) * 2 + h] = xn;
    }
}

extern "C" void kernel_launch(void* const* d_in, const int* in_sizes, int n_in,
                              void* d_out, int out_size, void* d_ws, size_t ws_size,
                              hipStream_t stream) {
    const float* x0   = (const float*)d_in[0];
    const float* W1   = (const float*)d_in[1];
    const float* b1   = (const float*)d_in[2];
    const float* W2   = (const float*)d_in[3];
    const float* Wout = (const float*)d_in[5];
    float* out = (float*)d_out;

    // workspace layout (floats); total ~10 MB
    float* ws   = (float*)d_ws;
    float* posA = ws;                        // 32768 (dead sink for last step)
    float* posB = posA + 32768;              // 32768
    float* x1   = posB + 32768;              // 262144
    float* Asp  = x1 + 262144;               // 16384*64 (4 MB, CEXP-scaled)
    float* Dsp  = Asp + 16384 * 64;          // 16384*64 (4 MB, CEXP-scaled)
    float* cut  = Dsp + 16384 * 64;          // 16384
    float2* sPosS = (float2*)(cut + 16384);                               // 16384 float2
    unsigned short* sIdx = (unsigned short*)(sPosS + 16384);              // 16384
    int* cellStart = (int*)(sIdx + 16384);                                // 8*320
    float* vArr = (float*)(cellStart + BB * CSTRIDE);                     // 64

    const int NB = (BB * NN) / WPB;          // 2048 blocks x 512 thr

    // step 0: x0 -> x1
    k_bin<true><<<BB, 1024, 0, stream>>>(x0, nullptr, W2, Wout, sPosS, sIdx,
                                         cellStart, vArr);
    k_cut<<<NB, BLOCK, 0, stream>>>(x0, sPosS, sIdx, cellStart, W1, cut, Asp, Dsp);
    k_grad<<<NB, BLOCK, 0, stream>>>(x0, sIdx, sPosS, cellStart, cut, Asp, Dsp,
                                     W1, b1, vArr, x1, posB);
    // step 1: x1 -> out
    k_bin<false><<<BB, 1024, 0, stream>>>(nullptr, posB, W2, Wout, sPosS, sIdx,
                                          cellStart, vArr);
    k_cut<<<NB, BLOCK, 0, stream>>>(x1, sPosS, sIdx, cellStart, W1, cut, Asp, Dsp);
    k_grad<<<NB, BLOCK, 0, stream>>>(x1, sIdx, sPosS, cellStart, cut, Asp, Dsp,
                                     W1, b1, vArr, out, posA);
}